// Round 2
// baseline (569.653 us; speedup 1.0000x reference)
//
#include <hip/hip_runtime.h>

#define LL 1024
#define NB 8
#define NT 256
#define RPT 4
#define C_EXP  (-14.426950408889634f)   // -10*log2(e)
#define C_LOG  (-0.069314718055994531f) // -(1/10)*ln(2)
#define EPS3   1e-12f

// e-space soft-DTW: e[i,j] = exp(-10*cost[i,j]) * ((e_dg + e_lf + e_up)/3 + eps)
// borders e=0 (D=100 -> exp(-1000)=0), origin e=1 (D=0).
// 256 threads = 4 waves; thread t owns rows 4t+1..4t+4 (1-indexed).
// Per diagonal step: all cross-row state flows in registers / 2 bpermutes;
// cross-wave boundary via parity-double-buffered LDS + one barrier.
__global__ __launch_bounds__(NT) void dtw_kernel(const float* __restrict__ outp,
                                                 const float* __restrict__ tgtp,
                                                 float* __restrict__ ws) {
  const int b = blockIdx.x;
  const int t = threadIdx.x;
  const int lane = t & 63;
  const int wv = t >> 6;

  __shared__ float y_s[LL + (LL >> 3)];   // padded: slot(j) = j + (j>>3), conflict-free
  __shared__ float bndE1[4][2];           // [wave][parity]
  __shared__ float bndE2[4][2];

  const float* xb = outp + (size_t)b * (LL * LL);
  const float* yb = tgtp + (size_t)b * (LL * LL);

  float X0 = xb[RPT * t + 0];
  float X1 = xb[RPT * t + 1];
  float X2 = xb[RPT * t + 2];
  float X3 = xb[RPT * t + 3];
#pragma unroll
  for (int m = 0; m < RPT; ++m) {
    int j = t + NT * m;
    y_s[j + (j >> 3)] = yb[j];
  }
  if (t < 8) { bndE1[t >> 1][t & 1] = 0.f; bndE2[t >> 1][t & 1] = 0.f; }
  __syncthreads();

  // E1 = e at diag k-1, E2 = e at diag k-2, for my 4 rows (a..d = rows 0..3)
  float E1a = 0.f, E1b = 0.f, E1c = 0.f, E1d = 0.f;
  float E2a = 0.f, E2b = 0.f, E2c = 0.f, E2d = 0.f;
  float Y0 = 0.f, Y1 = 0.f, Y2 = 0.f, Y3 = 0.f;   // y-value pipeline (flows down rows)
  float lastmm = EPS3;
  int yidx = -RPT * t;                    // row0's y index at current step (k - 4t - 2)
  const int addr_up = (lane == 0 ? 0 : (lane - 1)) << 2;
  const bool isLane0 = (lane == 0);
  const bool isT0 = (t == 0);
  const int wprev = (wv + 3) & 3;

  for (int k = 2; k <= 2 * LL; ++k) {
    const int par = k & 1, rpar = par ^ 1;
    // previous lane's last-row state as of end of previous step (wave-synchronous)
    float s1 = __int_as_float(__builtin_amdgcn_ds_bpermute(addr_up, __float_as_int(E1d)));
    float s2 = __int_as_float(__builtin_amdgcn_ds_bpermute(addr_up, __float_as_int(E2d)));
    float bE1 = bndE1[wprev][rpar];       // wave-uniform broadcast read
    float bE2 = bndE2[wprev][rpar];
    int yc = yidx & (LL - 1);             // clamp; OOB only when row 0 inactive
    float Ynew = y_s[yc + (yc >> 3)];
    if (isLane0) { s1 = bE1; s2 = bE2; }
    if (isT0)    { s1 = 0.f; s2 = (k == 2) ? 1.f : 0.f; }  // virtual row 0: borders / origin

    // shift y pipeline (row m uses what row m-1 used last step)
    Y3 = Y2; Y2 = Y1; Y1 = Y0; Y0 = Ynew;

    // compute all 4 rows reading OLD E1/E2 (rows are independent within a diagonal)
    float ec0 = __builtin_amdgcn_exp2f(fabsf(X0 - Y0) * C_EXP);
    float ec1 = __builtin_amdgcn_exp2f(fabsf(X1 - Y1) * C_EXP);
    float ec2 = __builtin_amdgcn_exp2f(fabsf(X2 - Y2) * C_EXP);
    float ec3 = __builtin_amdgcn_exp2f(fabsf(X3 - Y3) * C_EXP);
    float mm0 = fmaf(s2  + E1a + s1 , (1.f / 3.f), EPS3);  // a + bl + up
    float mm1 = fmaf(E2a + E1b + E1a, (1.f / 3.f), EPS3);
    float mm2 = fmaf(E2b + E1c + E1b, (1.f / 3.f), EPS3);
    float mm3 = fmaf(E2c + E1d + E1c, (1.f / 3.f), EPS3);
    float nv0 = ec0 * mm0;
    float nv1 = ec1 * mm1;
    float nv2 = ec2 * mm2;
    float nv3 = ec3 * mm3;
    lastmm = mm3;                          // only meaningful for t=NT-1 at k=2048

    // activity: row m interior iff 1 <= j_m <= 1024  <=>  (unsigned)(yidx-m) < 1024
    bool a0 = (unsigned)(yidx    ) < (unsigned)LL;
    bool a1 = (unsigned)(yidx - 1) < (unsigned)LL;
    bool a2 = (unsigned)(yidx - 2) < (unsigned)LL;
    bool a3 = (unsigned)(yidx - 3) < (unsigned)LL;
    E2a = E1a; E2b = E1b; E2c = E1c; E2d = E1d;
    E1a = a0 ? nv0 : E1a;
    E1b = a1 ? nv1 : E1b;
    E1c = a2 ? nv2 : E1c;
    E1d = a3 ? nv3 : E1d;

    if (lane == 63) { bndE1[wv][par] = E1d; bndE2[wv][par] = E2d; }
    ++yidx;
    __syncthreads();
  }

  if (t == NT - 1) {
    // D[1024,1024] = cost + (-1/10)*ln(m + eps); lastmm = m + eps from final cell
    float cost = fabsf(X3 - Y3);           // Y3 holds y[1023] after final step
    ws[b] = cost + C_LOG * __builtin_amdgcn_logf(lastmm);
  }
}

__global__ void reduce_mean(const float* __restrict__ ws, float* __restrict__ out) {
  if (threadIdx.x == 0 && blockIdx.x == 0) {
    float s = 0.f;
    for (int i = 0; i < NB; ++i) s += ws[i];
    out[0] = s * (1.0f / NB);
  }
}

extern "C" void kernel_launch(void* const* d_in, const int* in_sizes, int n_in,
                              void* d_out, int out_size, void* d_ws, size_t ws_size,
                              hipStream_t stream) {
  const float* o  = (const float*)d_in[0];
  const float* tg = (const float*)d_in[1];
  float* ws  = (float*)d_ws;
  float* out = (float*)d_out;

  dtw_kernel<<<NB, NT, 0, stream>>>(o, tg, ws);
  reduce_mean<<<1, 64, 0, stream>>>(ws, out);
}

// Round 3
// 291.807 us; speedup vs baseline: 1.9522x; 1.9522x over previous
//
#include <hip/hip_runtime.h>

#define LL   1024
#define NB   8
#define NT   256          // 4 waves
#define KCH  32           // steps per chunk (one barrier per chunk)
#define SKEW 320          // wall-step skew between adjacent strips (= 256 + 2*KCH)
#define TOT  2239         // 3*SKEW + (256 + 1024 - 1)
#define NCH  70           // ceil(TOT / KCH)
#define SMAX 1279         // local diagonals per 256-row strip
#define QSTR 384          // float2 slots per phase bucket
#define C10  14.426950408889634f        // 10*log2(e)
#define CLOG (-0.069314718055994531f)   // -(ln2)/10
#define EPS3 1e-12f

// Soft-DTW in e-space (e = exp(-10*D)), 4-wave skewed strip pipeline.
// Wave w owns global rows [256w+1, 256w+256]; lane l owns 4 contiguous rows.
// e[i,j] = min(en_i*fp_j, ep_i*fn_j) * ((e_dg+e_lf+e_up)/3 + eps), borders e=0.
// fp/fn zero-padded outside j in [1,1024] -> inactive cells self-compute 0.
__global__ __launch_bounds__(NT) void dtw_kernel(const float* __restrict__ outp,
                                                 const float* __restrict__ tgtp,
                                                 float* __restrict__ ws) {
  const int b = blockIdx.x;
  const int t = threadIdx.x;
  const int lane = t & 63;
  const int wvs = __builtin_amdgcn_readfirstlane(t >> 6);

  __shared__ float2 fpfn[4 * QSTR];   // [phase][q] swizzle: ji=j+256 -> (ji&3, ji>>2)
  __shared__ float  bnd[4][1032];     // strip-boundary rows; bnd[3] stays all-zero

  for (int i = t; i < 4 * QSTR; i += NT) fpfn[i] = make_float2(0.f, 0.f);
  for (int i = t; i < 4 * 1032; i += NT) (&bnd[0][0])[i] = 0.f;
  __syncthreads();

  const float* xb = outp + (size_t)b * LL * LL;
  const float* yb = tgtp + (size_t)b * LL * LL;

  // my 4 rows: global rows 256*wv + 4*lane + 1..4  (x index = row-1)
  const float4 xv = *(const float4*)(xb + 256 * wvs + 4 * lane);
  const float EP0 = __builtin_amdgcn_exp2f( C10 * xv.x), EN0 = __builtin_amdgcn_exp2f(-C10 * xv.x);
  const float EP1 = __builtin_amdgcn_exp2f( C10 * xv.y), EN1 = __builtin_amdgcn_exp2f(-C10 * xv.y);
  const float EP2 = __builtin_amdgcn_exp2f( C10 * xv.z), EN2 = __builtin_amdgcn_exp2f(-C10 * xv.z);
  const float EP3 = __builtin_amdgcn_exp2f( C10 * xv.w), EN3 = __builtin_amdgcn_exp2f(-C10 * xv.w);

  {
    const float4 yv = *(const float4*)(yb + 4 * t);
    const float yy[4] = {yv.x, yv.y, yv.z, yv.w};
#pragma unroll
    for (int m = 0; m < 4; ++m) {
      const int ji = (4 * t + 1 + m) + 256;           // column j = 4t+1+m
      fpfn[(ji & 3) * QSTR + (ji >> 2)] =
          make_float2(__builtin_amdgcn_exp2f( C10 * yy[m]),
                      __builtin_amdgcn_exp2f(-C10 * yy[m]));
    }
  }
  const float costL = (t == NT - 1) ? fabsf(xv.w - yb[LL - 1]) : 0.f;
  __syncthreads();

  float E1a = 0.f, E1b = 0.f, E1c = 0.f, E1d = 0.f;
  float E2a = 0.f, E2b = 0.f, E2c = 0.f;
  float up_del = (t == 0) ? 1.f : 0.f;    // diag source for row a; e[0,0]=1 seed
  float fpp[4] = {0.f, 0.f, 0.f, 0.f};
  float fnp[4] = {0.f, 0.f, 0.f, 0.f};
  float lastmm = EPS3;
  const int addr_up = ((lane - 1) & 63) << 2;
  const int wprev = (wvs + 3) & 3;        // wave 0 reads bnd[3] (all zeros)
  // byte offset of q-part: q(s) = floor((s+256)/4) - lane, at s_start = 1 - SKEW*wv
  int vq = (((257 - SKEW * wvs) >> 2) - lane) * 8;

  for (int c = 0; c < NCH; ++c) {
    const int sb = c * KCH + 1 - SKEW * wvs;   // local step s at r=0 (s == 1 mod 4)
    for (int u8 = 0; u8 < KCH; u8 += 8) {
#pragma unroll
      for (int r = 0; r < 8; ++r) {
        if ((r & 3) == 3) vq += 8;             // q bump when s == 0 (mod 4)
        const int s = sb + u8 + r;
        if (s >= 1 && s <= SMAX) {
          const int P = (1 + r) & 3;           // phase = s & 3 (sb==1 mod 4, u8==0 mod 4)
          // neighbor's bottom-row e (end of previous step) — read before commit
          const float up_nb = __int_as_float(
              __builtin_amdgcn_ds_bpermute(addr_up, __float_as_int(E1d)));
          const float bval = bnd[wprev][(s < 1024) ? s : 1024];  // broadcast
          const float up_a = (lane == 0) ? bval : up_nb;
          const float2 f2 = *(const float2*)((const char*)fpfn + (P * (QSTR * 8) + vq));
          fpp[P] = f2.x; fnp[P] = f2.y;
          // ec = exp(-10*|x_i - y_j|) via min of exp-products (overflow-safe)
          const float eca = fminf(EN0 * fpp[P],           EP0 * fnp[P]);
          const float ecb = fminf(EN1 * fpp[(P + 3) & 3], EP1 * fnp[(P + 3) & 3]);
          const float ecc = fminf(EN2 * fpp[(P + 2) & 3], EP2 * fnp[(P + 2) & 3]);
          const float ecd = fminf(EN3 * fpp[(P + 1) & 3], EP3 * fnp[(P + 1) & 3]);
          const float mma = fmaf(up_del + E1a + up_a, (1.f / 3.f), EPS3);
          const float mmb = fmaf(E2a + E1b + E1a, (1.f / 3.f), EPS3);
          const float mmc = fmaf(E2b + E1c + E1b, (1.f / 3.f), EPS3);
          const float mmd = fmaf(E2c + E1d + E1c, (1.f / 3.f), EPS3);
          const float nva = eca * mma, nvb = ecb * mmb;
          const float nvc = ecc * mmc, nvd = ecd * mmd;
          E2a = E1a; E2b = E1b; E2c = E1c;
          E1a = nva; E1b = nvb; E1c = nvc; E1d = nvd;
          up_del = up_a;
          lastmm = mmd;
          if (wvs < 3 && s >= 256) {           // bottom row active: column s-255
            if (lane == 63) bnd[wvs][s - 255] = nvd;
          }
        }
      }
    }
    __syncthreads();
  }

  // D[1024,1024] = cost + (-1/10)*ln(m + eps); computed by wave 3 lane 63 row d at s=1279
  if (t == NT - 1) ws[b] = costL + CLOG * __builtin_amdgcn_logf(lastmm);
}

__global__ void reduce_mean(const float* __restrict__ ws, float* __restrict__ out) {
  if (threadIdx.x == 0 && blockIdx.x == 0) {
    float s = 0.f;
    for (int i = 0; i < NB; ++i) s += ws[i];
    out[0] = s * (1.0f / NB);
  }
}

extern "C" void kernel_launch(void* const* d_in, const int* in_sizes, int n_in,
                              void* d_out, int out_size, void* d_ws, size_t ws_size,
                              hipStream_t stream) {
  const float* o  = (const float*)d_in[0];
  const float* tg = (const float*)d_in[1];
  float* ws  = (float*)d_ws;
  float* out = (float*)d_out;

  dtw_kernel<<<NB, NT, 0, stream>>>(o, tg, ws);
  reduce_mean<<<1, 64, 0, stream>>>(ws, out);
}

// Round 4
// 220.689 us; speedup vs baseline: 2.5812x; 1.3223x over previous
//
#include <hip/hip_runtime.h>

#define LL    1024
#define NB    8
#define NT    256          // 4 waves
#define KCH   32           // steps per chunk (one barrier per chunk)
#define SKEW  288          // = KCH + 256, exact producer->consumer visibility bound
#define SMAX  1279         // local diagonals per 256-row strip
#define NCH   67           // ceil((3*SKEW + SMAX) / KCH) = ceil(2143/32)
#define QSTR  384          // float2 slots per phase bucket (in-use q: 64..320)
#define BROW  1312         // bndX row stride (floats); idx = col + BOFF
#define BOFF  270
#define C10   14.426950408889634f        // 10*log2(e)
#define CLOG  (-0.069314718055994531f)   // -(ln2)/10
#define EPS3  1e-12f

// Soft-DTW in e-space (e = exp(-10*D)), 4-wave skewed strip pipeline.
// Round-4: per-step DS ops reduced to {1 bpermute, 1 ds_write}; fpfn and the
// strip-boundary row are chunk-prefetched into registers (readlane trick).

// Core of one wavefront step, r must be a literal-constant expression.
// Order: row d -> issue bpermute(next) -> rows c,b -> consume prev bpermute -> row a.
#define STEPCORE(r, WRSTMT)                                                   \
    const int   P_ = ((r) + 1) & 3;                                           \
    const int   o_ = (r) >> 2;                                                \
    const float4 fq_ = FQ[P_][o_ >> 1];                                       \
    fpp[P_] = (o_ & 1) ? fq_.z : fq_.x;                                       \
    fnp[P_] = (o_ & 1) ? fq_.w : fq_.y;                                       \
    const float ecd_ = fminf(EN3 * fpp[(P_ + 1) & 3], EP3 * fnp[(P_ + 1) & 3]); \
    const float mmd_ = fmaf(E2c + E1d + E1c, (1.f / 3.f), EPS3);              \
    const float nvd_ = ecd_ * mmd_;                                           \
    const float BPn_ = __int_as_float(                                        \
        __builtin_amdgcn_ds_bpermute(addr_up, __float_as_int(nvd_)));         \
    const float ecc_ = fminf(EN2 * fpp[(P_ + 2) & 3], EP2 * fnp[(P_ + 2) & 3]); \
    const float mmc_ = fmaf(E2b + E1c + E1b, (1.f / 3.f), EPS3);              \
    const float nvc_ = ecc_ * mmc_;                                           \
    const float ecb_ = fminf(EN1 * fpp[(P_ + 3) & 3], EP1 * fnp[(P_ + 3) & 3]); \
    const float mmb_ = fmaf(E2a + E1b + E1a, (1.f / 3.f), EPS3);              \
    const float nvb_ = ecb_ * mmb_;                                           \
    const int   bvi_ = __builtin_amdgcn_readlane(__float_as_int(B), (r));     \
    const float up_a_ = isL0 ? __int_as_float(bvi_) : BPres;                  \
    const float eca_ = fminf(EN0 * fpp[P_], EP0 * fnp[P_]);                   \
    const float mma_ = fmaf(up_del + E1a + up_a_, (1.f / 3.f), EPS3);         \
    const float nva_ = eca_ * mma_;                                           \
    WRSTMT                                                                    \
    E2a = E1a; E2b = E1b; E2c = E1c;                                          \
    E1a = nva_; E1b = nvb_; E1c = nvc_; E1d = nvd_;                           \
    up_del = up_a_; BPres = BPn_; lastmm = mmd_;

#define STEPF(r) do { STEPCORE(r, wbase[(r)] = nvd_;) } while (0)
#define STEPG(r) do {                                                         \
    const int s_ = sb + (r);                                                  \
    if (s_ >= 1 && s_ <= SMAX) {                                              \
      STEPCORE(r, if (lane == 63) bndX[wwr][s_ + 15] = nvd_;)                 \
    }                                                                         \
  } while (0)

#define DO8(M, B8)  M(B8 + 0); M(B8 + 1); M(B8 + 2); M(B8 + 3);               \
                    M(B8 + 4); M(B8 + 5); M(B8 + 6); M(B8 + 7)
#define DO32(M)     DO8(M, 0); DO8(M, 8); DO8(M, 16); DO8(M, 24)

__global__ __launch_bounds__(NT, 1) void dtw_kernel(const float* __restrict__ outp,
                                                    const float* __restrict__ tgtp,
                                                    float* __restrict__ ws) {
  const int b = blockIdx.x;
  const int t = threadIdx.x;
  const int lane = t & 63;
  const int wvs = __builtin_amdgcn_readfirstlane(t >> 6);

  __shared__ float2 fpfn[4 * QSTR];   // phase-bucketed (fp,fn) table, zero guard zones
  __shared__ float  bndX[5][BROW];    // rows 0-2: strip boundaries; 3: zero; 4: wave-3 dump
  __shared__ float  dumpA[4][128];    // per-wave dump for non-lane-63 boundary writes

  {
    float4* zf = (float4*)&fpfn[0];
    for (int i = t; i < 768; i += NT) zf[i] = make_float4(0.f, 0.f, 0.f, 0.f);
    float4* zb = (float4*)&bndX[0][0];
    for (int i = t; i < 1640; i += NT) zb[i] = make_float4(0.f, 0.f, 0.f, 0.f);
  }
  __syncthreads();

  const float* xb = outp + (size_t)b * LL * LL;
  const float* yb = tgtp + (size_t)b * LL * LL;

  const float4 xv = *(const float4*)(xb + 256 * wvs + 4 * lane);
  const float EP0 = __builtin_amdgcn_exp2f( C10 * xv.x), EN0 = __builtin_amdgcn_exp2f(-C10 * xv.x);
  const float EP1 = __builtin_amdgcn_exp2f( C10 * xv.y), EN1 = __builtin_amdgcn_exp2f(-C10 * xv.y);
  const float EP2 = __builtin_amdgcn_exp2f( C10 * xv.z), EN2 = __builtin_amdgcn_exp2f(-C10 * xv.z);
  const float EP3 = __builtin_amdgcn_exp2f( C10 * xv.w), EN3 = __builtin_amdgcn_exp2f(-C10 * xv.w);

  {
    const float4 yv = *(const float4*)(yb + 4 * t);
    const float yy[4] = {yv.x, yv.y, yv.z, yv.w};
#pragma unroll
    for (int q = 0; q < 4; ++q) {
      const int ji = (4 * t + 1 + q) + 256;
      fpfn[(ji & 3) * QSTR + (ji >> 2)] =
          make_float2(__builtin_amdgcn_exp2f( C10 * yy[q]),
                      __builtin_amdgcn_exp2f(-C10 * yy[q]));
    }
  }
  const float costL = (t == NT - 1) ? fabsf(xv.w - yb[LL - 1]) : 0.f;
  __syncthreads();

  float fpp[4] = {0.f, 0.f, 0.f, 0.f};
  float fnp[4] = {0.f, 0.f, 0.f, 0.f};
  float E1a = 0.f, E1b = 0.f, E1c = 0.f, E1d = 0.f;
  float E2a = 0.f, E2b = 0.f, E2c = 0.f;
  float up_del = (t == 0) ? 1.f : 0.f;   // e[0,0] = 1 seed (diag of cell (1,1))
  float BPres = 0.f;
  float lastmm = EPS3;
  const bool isL0 = (lane == 0);
  const int addr_up = ((lane - 1) & 63) << 2;
  const int wprev = (wvs == 0) ? 3 : (wvs - 1);
  const int wwr   = (wvs == 3) ? 4 : wvs;

#pragma unroll 1
  for (int c = 0; c < NCH; ++c) {
    const int sb = c * KCH + 1 - SKEW * wvs;
    if (sb > SMAX || sb + (KCH - 1) < 1) { __syncthreads(); continue; }

    // boundary-row chunk preload: lane l holds bnd value for step sb+l
    int colp = sb + lane;
    colp = colp < 0 ? 0 : (colp > 1024 ? 1024 : colp);
    const float B = bndX[wprev][colp + BOFF];

    // fpfn chunk prefetch: per phase, 8 consecutive q slots = 4 x ds_read_b128
    const int m_ = (sb + 255) >> 2;     // exact: sb+255 always divisible by 4
    float4 FQ[4][4];
#pragma unroll
    for (int P = 0; P < 4; ++P) {
      int qb = ((P == 0 ? m_ + 1 : m_) - lane) * 8;
      qb = qb < 0 ? 0 : qb;
      qb = qb > (QSTR - 8) * 8 ? (QSTR - 8) * 8 : qb;   // clamps land in zero zones
      const char* bp = (const char*)fpfn + P * (QSTR * 8) + qb;
      FQ[P][0] = *(const float4*)(bp);
      FQ[P][1] = *(const float4*)(bp + 16);
      FQ[P][2] = *(const float4*)(bp + 32);
      FQ[P][3] = *(const float4*)(bp + 48);
    }

    if (sb >= 1 && sb + (KCH - 1) <= SMAX) {
      float* wbase = (lane == 63) ? &bndX[wwr][sb + 15] : &dumpA[wvs][lane];
      DO32(STEPF);
    } else {
      DO32(STEPG);
    }
    __syncthreads();
  }

  // D[1024,1024] = cost + (-1/10)*ln(m + eps); wave 3, lane 63, row d, s=1279
  if (t == NT - 1) ws[b] = costL + CLOG * __builtin_amdgcn_logf(lastmm);
}

__global__ void reduce_mean(const float* __restrict__ ws, float* __restrict__ out) {
  if (threadIdx.x == 0 && blockIdx.x == 0) {
    float s = 0.f;
    for (int i = 0; i < NB; ++i) s += ws[i];
    out[0] = s * (1.0f / NB);
  }
}

extern "C" void kernel_launch(void* const* d_in, const int* in_sizes, int n_in,
                              void* d_out, int out_size, void* d_ws, size_t ws_size,
                              hipStream_t stream) {
  const float* o  = (const float*)d_in[0];
  const float* tg = (const float*)d_in[1];
  float* ws  = (float*)d_ws;
  float* out = (float*)d_out;

  dtw_kernel<<<NB, NT, 0, stream>>>(o, tg, ws);
  reduce_mean<<<1, 64, 0, stream>>>(ws, out);
}

// Round 5
// 159.346 us; speedup vs baseline: 3.5749x; 1.3850x over previous
//
#include <hip/hip_runtime.h>

#define LL    1024
#define NB    8
#define NT    256          // 4 waves
#define KCH   32           // steps per chunk (one barrier per chunk)
#define SKEW  288          // wall-step skew between adjacent strips
#define SMAX  1279         // last local diagonal of a 256-row strip
#define NCH   67           // wave w active chunks: c in [9w, 9w+39]
#define YTN   1536         // linear y-table entries (float2), ji = j + 256
#define BROW  1312         // bndX row stride (floats)
#define BOFF  270          // col 0 of a boundary row lives at index BOFF
#define C10   14.426950408889634f        // 10*log2(e)
#define CLOG  (-0.069314718055994531f)   // -(ln2)/10
#define EPS3  1e-12f

// Soft-DTW in e-space (e = exp(-10*D)); 4-wave skewed strip pipeline.
// Round-5: per-step LDS latency removed from the critical path:
//  - y-table streamed through 2x4 float4 register buffers (static k-index macros)
//  - up-neighbor via DPP row_shr:1 (bpermute only covers lanes 16/32/48)
//  - strip-boundary row via chunk-preloaded register + readlane
// All guards are zero table entries -> out-of-range cells self-compute e=0.

// y-stream access, k is a literal in [-3, 31]: buffer = ((k>>3)&1) ? Bv : Av
#define YB4(k) (((((k) >> 3) & 1) != 0)                                        \
    ? (((((k) & 7) >> 1) == 0) ? Bv0 : ((((k) & 7) >> 1) == 1) ? Bv1           \
                               : ((((k) & 7) >> 1) == 2) ? Bv2 : Bv3)          \
    : (((((k) & 7) >> 1) == 0) ? Av0 : ((((k) & 7) >> 1) == 1) ? Av1           \
                               : ((((k) & 7) >> 1) == 2) ? Av2 : Av3))
#define FPE(k) ((((k) & 1) != 0) ? YB4(k).z : YB4(k).x)
#define FNE(k) ((((k) & 1) != 0) ? YB4(k).w : YB4(k).y)

#define STEP(r) do {                                                           \
    const float ecd_ = fminf(EN3 * FPE((r) - 3), EP3 * FNE((r) - 3));          \
    const float mmd_ = fmaf(E2c + E1d + E1c, (1.f / 3.f), EPS3);               \
    const float nvd_ = ecd_ * mmd_;                                            \
    const float dppv_ = __int_as_float(__builtin_amdgcn_update_dpp(            \
        0, __float_as_int(E1d), 0x111, 0xf, 0xf, true)); /* row_shr:1 */       \
    const float bpn_ = __int_as_float(                                         \
        __builtin_amdgcn_ds_bpermute(addr_up, __float_as_int(nvd_)));          \
    wbase[(r)] = nvd_;                                                         \
    const float ecc_ = fminf(EN2 * FPE((r) - 2), EP2 * FNE((r) - 2));          \
    const float mmc_ = fmaf(E2b + E1c + E1b, (1.f / 3.f), EPS3);               \
    const float nvc_ = ecc_ * mmc_;                                            \
    const float ecb_ = fminf(EN1 * FPE((r) - 1), EP1 * FNE((r) - 1));          \
    const float mmb_ = fmaf(E2a + E1b + E1a, (1.f / 3.f), EPS3);               \
    const float nvb_ = ecb_ * mmb_;                                            \
    const float bvs_ = __int_as_float(                                         \
        __builtin_amdgcn_readlane(__float_as_int(B), (r)));                    \
    const float upn_ = is16 ? BPres : dppv_;                                   \
    const float upa_ = isL0 ? bvs_ : upn_;                                     \
    const float eca_ = fminf(EN0 * FPE(r), EP0 * FNE(r));                      \
    const float mma_ = fmaf(up_del + E1a + upa_, (1.f / 3.f), EPS3);           \
    const float nva_ = eca_ * mma_;                                            \
    E2a = E1a; E2b = E1b; E2c = E1c;                                           \
    E1a = nva_; E1b = nvb_; E1c = nvc_; E1d = nvd_;                            \
    up_del = upa_; BPres = bpn_; lastmm = mmd_;                                \
  } while (0)

#define LD4(dst0, dst1, dst2, dst3, byteoff) do {                              \
    const char* p_ = (const char*)ytab + (byteoff);                            \
    dst0 = *(const float4*)(p_);                                               \
    dst1 = *(const float4*)(p_ + 16);                                          \
    dst2 = *(const float4*)(p_ + 32);                                          \
    dst3 = *(const float4*)(p_ + 48);                                          \
  } while (0)

__global__ __launch_bounds__(NT, 1) void dtw_kernel(const float* __restrict__ outp,
                                                    const float* __restrict__ tgtp,
                                                    float* __restrict__ ws) {
  const int b = blockIdx.x;
  const int t = threadIdx.x;
  const int lane = t & 63;
  const int wvs = __builtin_amdgcn_readfirstlane(t >> 6);

  __shared__ float2 ytab[YTN];        // linear (fp,fn) table, zero guards outside j=1..1024
  __shared__ float  bndX[5][BROW];    // 0-2: strip boundaries; 3: zeros+seed; 4: wave-3 dump
  __shared__ float  dumpA[4][128];    // scratch sink for non-lane-63 boundary writes

  {
    float4* zf = (float4*)&ytab[0];
    for (int i = t; i < (YTN * 2) / 4; i += NT) zf[i] = make_float4(0.f, 0.f, 0.f, 0.f);
    float4* zb = (float4*)&bndX[0][0];
    for (int i = t; i < (5 * BROW) / 4; i += NT) zb[i] = make_float4(0.f, 0.f, 0.f, 0.f);
  }
  __syncthreads();

  const float* xb = outp + (size_t)b * LL * LL;
  const float* yb = tgtp + (size_t)b * LL * LL;

  // my 4 rows: global rows 256*wvs + 4*lane + 1..4
  const float4 xv = *(const float4*)(xb + 256 * wvs + 4 * lane);
  const float EP0 = __builtin_amdgcn_exp2f( C10 * xv.x), EN0 = __builtin_amdgcn_exp2f(-C10 * xv.x);
  const float EP1 = __builtin_amdgcn_exp2f( C10 * xv.y), EN1 = __builtin_amdgcn_exp2f(-C10 * xv.y);
  const float EP2 = __builtin_amdgcn_exp2f( C10 * xv.z), EN2 = __builtin_amdgcn_exp2f(-C10 * xv.z);
  const float EP3 = __builtin_amdgcn_exp2f( C10 * xv.w), EN3 = __builtin_amdgcn_exp2f(-C10 * xv.w);

  {
    const float4 yv = *(const float4*)(yb + 4 * t);
    const float yy[4] = {yv.x, yv.y, yv.z, yv.w};
#pragma unroll
    for (int q = 0; q < 4; ++q) {
      const int ji = (4 * t + 1 + q) + 256;            // j = 4t+1+q in [1,1024]
      ytab[ji] = make_float2(__builtin_amdgcn_exp2f( C10 * yy[q]),
                             __builtin_amdgcn_exp2f(-C10 * yy[q]));
    }
  }
  if (t == 0) bndX[3][BOFF] = 1.0f;   // e[0,0] = 1 seed, read by wave 0 lane 0 at s=0
  const float costL = (t == NT - 1) ? fabsf(xv.w - yb[LL - 1]) : 0.f;
  __syncthreads();

  float E1a = 0.f, E1b = 0.f, E1c = 0.f, E1d = 0.f;
  float E2a = 0.f, E2b = 0.f, E2c = 0.f;
  float up_del = 0.f, BPres = 0.f, lastmm = EPS3;
  float4 Av0, Av1, Av2, Av3;
  float4 Bv0 = make_float4(0.f, 0.f, 0.f, 0.f), Bv1 = Bv0, Bv2 = Bv0, Bv3 = Bv0;
  const bool isL0 = (lane == 0);
  const bool is16 = ((lane & 15) == 0);
  const int addr_up = ((lane - 1) & 63) << 2;
  const int wprev = (wvs == 0) ? 3 : (wvs - 1);
  const int wwr   = (wvs == 3) ? 4 : wvs;

#pragma unroll 1
  for (int c = 0; c < NCH; ++c) {
    const int sb = KCH * c - SKEW * wvs;   // local step of r=0; sb ≡ 0 (mod 32)
    if (sb < 0 || sb > SMAX - (KCH - 1)) { __syncthreads(); continue; }

    // strip-boundary preload: lane l holds producer value for step sb+l (col sb+l)
    int colp = sb + lane; colp = colp > LL ? LL : colp;
    const float B = bndX[wprev][colp + BOFF];

    // y-stream: group-g leading entries are ji = sb + 8g - 4*lane + 256 .. +7
    const int base0 = 8 * (sb - 4 * lane + 256);   // 16B-aligned (even entry index)
    LD4(Av0, Av1, Av2, Av3, base0);                // g0; Bv* still holds prev g3 (k<0)

    float* wbase = (lane == 63) ? &bndX[wwr][sb + 15] : &dumpA[wvs][lane];

    STEP(0); STEP(1); STEP(2);
    LD4(Bv0, Bv1, Bv2, Bv3, base0 + 64);           // g1 (entries 8..15); first use r=8
    STEP(3); STEP(4); STEP(5); STEP(6); STEP(7);
    STEP(8); STEP(9); STEP(10);
    LD4(Av0, Av1, Av2, Av3, base0 + 128);          // g2 (entries 16..23); first use r=16
    STEP(11); STEP(12); STEP(13); STEP(14); STEP(15);
    STEP(16); STEP(17); STEP(18);
    LD4(Bv0, Bv1, Bv2, Bv3, base0 + 192);          // g3 (entries 24..31); first use r=24
    STEP(19); STEP(20); STEP(21); STEP(22); STEP(23);
    STEP(24); STEP(25); STEP(26); STEP(27); STEP(28); STEP(29); STEP(30); STEP(31);
    __syncthreads();
  }

  // wave 3, lane 63, s=1279 is the final executed step -> lastmm = m + eps at (1024,1024)
  if (t == NT - 1) ws[b] = costL + CLOG * __builtin_amdgcn_logf(lastmm);
}

__global__ void reduce_mean(const float* __restrict__ ws, float* __restrict__ out) {
  if (threadIdx.x == 0 && blockIdx.x == 0) {
    float s = 0.f;
    for (int i = 0; i < NB; ++i) s += ws[i];
    out[0] = s * (1.0f / NB);
  }
}

extern "C" void kernel_launch(void* const* d_in, const int* in_sizes, int n_in,
                              void* d_out, int out_size, void* d_ws, size_t ws_size,
                              hipStream_t stream) {
  const float* o  = (const float*)d_in[0];
  const float* tg = (const float*)d_in[1];
  float* ws  = (float*)d_ws;
  float* out = (float*)d_out;

  dtw_kernel<<<NB, NT, 0, stream>>>(o, tg, ws);
  reduce_mean<<<1, 64, 0, stream>>>(ws, out);
}

// Round 6
// 124.058 us; speedup vs baseline: 4.5918x; 1.2844x over previous
//
#include <hip/hip_runtime.h>

#define LL    1024
#define NB    8
#define NT    256          // 4 waves per WG
#define KCH   32           // steps per chunk (one barrier per chunk)
#define SKEW  160          // intra-WG wall-step skew (= 128 rows + KCH)
#define SMAX  1151         // last local diagonal of a 128-row strip (127 + 1024)
#define NCH   52           // chunks per WG (covers sb up to 1120 + export flush)
#define YTN   1536         // linear y-table entries (float2), ji = j + 256
#define BROW  1160         // bndX row stride (floats)
#define BOFF  128          // col 0 of a boundary row at index BOFF
#define GBASE 64           // d_ws float offset of link regions
#define GSTR  1280         // per-batch link region stride (floats): 128 guard + 1025 cols
#define GDUMP (GBASE + 8 * GSTR)
#define C10   14.426950408889634f        // 10*log2(e)
#define CLOG  (-0.069314718055994531f)   // -(ln2)/10
#define EPS3  1e-12f

// Soft-DTW in e-space (e = exp(-10*D)); 8 strips/batch across 2 WGs (16 CUs).
// Intra-WG: LDS boundary rows + barrier-per-chunk (round-5 proven machinery).
// Inter-WG: producer (WG0 wave 3) exports bottom row via relaxed agent-scope
// atomic stores; consumer (WG1 wave 0) prefetches 1 chunk ahead and validates
// by sentinel (values >= 0 are ready; 0xAA poison / -1 fill are negative).

#define YB4(k) (((((k) >> 3) & 1) != 0)                                        \
    ? (((((k) & 7) >> 1) == 0) ? Bv0 : ((((k) & 7) >> 1) == 1) ? Bv1           \
                               : ((((k) & 7) >> 1) == 2) ? Bv2 : Bv3)          \
    : (((((k) & 7) >> 1) == 0) ? Av0 : ((((k) & 7) >> 1) == 1) ? Av1           \
                               : ((((k) & 7) >> 1) == 2) ? Av2 : Av3))
#define FPE(k) ((((k) & 1) != 0) ? YB4(k).z : YB4(k).x)
#define FNE(k) ((((k) & 1) != 0) ? YB4(k).w : YB4(k).y)

// rows per lane: a = 2*lane, b = 2*lane+1 (strip-local). Cell (rr,j) at s=rr+j.
#define STEP(r) do {                                                           \
    const float ecb_ = fminf(EN1 * FPE((r) - 1), EP1 * FNE((r) - 1));          \
    const float mmb_ = fmaf(E2a + E1b + E1a, (1.f / 3.f), EPS3);               \
    const float nvb_ = ecb_ * mmb_;                                            \
    const float dppv_ = __int_as_float(__builtin_amdgcn_update_dpp(            \
        0, __float_as_int(E1b), 0x111, 0xf, 0xf, true)); /* row_shr:1 */       \
    const float bpn_ = __int_as_float(                                         \
        __builtin_amdgcn_ds_bpermute(addr_up, __float_as_int(nvb_)));          \
    wbase[(r)] = nvb_;                                                         \
    const float bvs_ = __int_as_float(                                         \
        __builtin_amdgcn_readlane(__float_as_int(B), (r)));                    \
    const float upn_ = is16 ? BPres : dppv_;                                   \
    const float upa_ = isL0 ? bvs_ : upn_;                                     \
    const float eca_ = fminf(EN0 * FPE(r), EP0 * FNE(r));                      \
    const float mma_ = fmaf(up_del + E1a + upa_, (1.f / 3.f), EPS3);           \
    const float nva_ = eca_ * mma_;                                            \
    E2a = E1a;                                                                 \
    E1a = nva_; E1b = nvb_;                                                    \
    up_del = upa_; BPres = bpn_; lastmm = mmb_;                                \
  } while (0)

#define LD4(d0, d1, d2, d3, byteoff) do {                                      \
    const char* p_ = (const char*)ytab + (byteoff);                            \
    d0 = *(const float4*)(p_);                                                 \
    d1 = *(const float4*)(p_ + 16);                                            \
    d2 = *(const float4*)(p_ + 32);                                            \
    d3 = *(const float4*)(p_ + 48);                                            \
  } while (0)

__global__ __launch_bounds__(NT, 1) void dtw_kernel(const float* __restrict__ outp,
                                                    const float* __restrict__ tgtp,
                                                    float* __restrict__ wsf) {
  const int bb = blockIdx.x >> 1;      // batch
  const int wg = blockIdx.x & 1;       // 0 = rows 1..512, 1 = rows 513..1024
  const int t = threadIdx.x;
  const int lane = t & 63;
  const int wvs = __builtin_amdgcn_readfirstlane(t >> 6);

  __shared__ float2 ytab[YTN];        // zero-guarded (fp,fn) table
  __shared__ float  bndX[5][BROW];    // rows 0-2: waves 0-2 boundaries; 3: zeros+seed; 4: wave-3 staging
  __shared__ float  dumpA[4][128];    // LDS sink for non-lane-63 boundary writes

  {
    float4* zf = (float4*)&ytab[0];
    for (int i = t; i < (YTN * 2) / 4; i += NT) zf[i] = make_float4(0.f, 0.f, 0.f, 0.f);
    float4* zb = (float4*)&bndX[0][0];
    for (int i = t; i < (5 * BROW) / 4; i += NT) zb[i] = make_float4(0.f, 0.f, 0.f, 0.f);
  }
  __syncthreads();

  const float* xb = outp + (size_t)bb * LL * LL;
  const float* yb = tgtp + (size_t)bb * LL * LL;
  float* gcols = wsf + GBASE + bb * GSTR + 128;   // link cols 0..1024 (128-float guard below)
  float* gdump = wsf + GDUMP;

  // my 2 rows: global rows 512*wg + 128*wvs + 2*lane + {1,2}
  const float2 xv = *(const float2*)(xb + 512 * wg + 128 * wvs + 2 * lane);
  const float EP0 = __builtin_amdgcn_exp2f( C10 * xv.x), EN0 = __builtin_amdgcn_exp2f(-C10 * xv.x);
  const float EP1 = __builtin_amdgcn_exp2f( C10 * xv.y), EN1 = __builtin_amdgcn_exp2f(-C10 * xv.y);

  {
    const float4 yv = *(const float4*)(yb + 4 * t);
    const float yy[4] = {yv.x, yv.y, yv.z, yv.w};
#pragma unroll
    for (int q = 0; q < 4; ++q) {
      const int ji = (4 * t + 1 + q) + 256;          // j in [1,1024]
      ytab[ji] = make_float2(__builtin_amdgcn_exp2f( C10 * yy[q]),
                             __builtin_amdgcn_exp2f(-C10 * yy[q]));
    }
  }
  if (wg == 0 && t == 0) bndX[3][BOFF] = 1.0f;      // e[0,0] = 1 seed
  const float costL = (wg == 1 && t == NT - 1) ? fabsf(xv.y - yb[LL - 1]) : 0.f;
  __syncthreads();

  float E1a = 0.f, E1b = 0.f, E2a = 0.f;
  float up_del = 0.f, BPres = 0.f, lastmm = EPS3;
  float4 Av0, Av1, Av2, Av3;
  float4 Bv0 = make_float4(0.f, 0.f, 0.f, 0.f), Bv1 = Bv0, Bv2 = Bv0, Bv3 = Bv0;
  Av0 = Bv0; Av1 = Bv0; Av2 = Bv0; Av3 = Bv0;
  const bool isL0 = (lane == 0);
  const bool is16 = ((lane & 15) == 0);
  const int addr_up = ((lane - 1) & 63) << 2;
  const int wprev = (wvs == 0) ? 3 : (wvs - 1);
  const int wwr   = (wvs == 3) ? 4 : wvs;
  const bool isProd = (wg == 0) && (wvs == 3);
  const bool isCons = (wg == 1) && (wvs == 0);

  float Bnext = 0.f;
  int*  pcur  = (int*)gcols;
  if (isCons) {
    // sentinel-fill our link region (robust to any initial d_ws content)
    for (int c0 = lane; c0 <= LL; c0 += 64)
      __hip_atomic_store((int*)(gcols + c0), __float_as_int(-1.0f),
                         __ATOMIC_RELAXED, __HIP_MEMORY_SCOPE_AGENT);
    __threadfence();
    pcur = (int*)(gcols + lane);
    Bnext = __int_as_float(__hip_atomic_load(pcur, __ATOMIC_RELAXED, __HIP_MEMORY_SCOPE_AGENT));
  }

#pragma unroll 1
  for (int c = 0; c < NCH; ++c) {
    const int sb = KCH * c - SKEW * wvs;   // local step at r=0 (multiple of 32)

    if (isProd && sb >= KCH) {             // export 2-chunks-back window (always already staged)
      int ec = sb - 191 + lane;
      ec = ec < 0 ? 0 : (ec > LL ? LL : ec);
      const float ev = bndX[4][ec + BOFF];
      __hip_atomic_store((int*)(gcols + ec), __float_as_int(ev),
                         __ATOMIC_RELAXED, __HIP_MEMORY_SCOPE_AGENT);
    }

    if (sb < 0 || sb > SMAX - (KCH - 1)) { __syncthreads(); continue; }

    // boundary preload: lane l holds up-value for step sb+l (col sb+l)
    float B;
    if (isCons) {
      float bv = Bnext;
      for (int tries = 0;
           (__ballot(bv < 0.f) & 0xffffffffull) && tries < (1 << 16); ++tries) {
        __builtin_amdgcn_s_sleep(8);
        bv = __int_as_float(__hip_atomic_load(pcur, __ATOMIC_RELAXED, __HIP_MEMORY_SCOPE_AGENT));
      }
      B = bv;
      int cn = sb + KCH + lane; cn = cn > LL ? LL : cn;       // prefetch next chunk
      pcur = (int*)(gcols + cn);
      Bnext = __int_as_float(__hip_atomic_load(pcur, __ATOMIC_RELAXED, __HIP_MEMORY_SCOPE_AGENT));
    } else {
      int colp = sb + lane; colp = colp > LL ? LL : colp;
      B = bndX[wprev][colp + BOFF];
    }

    // y-stream chunk loads: entries ji0 + [0,31], ji0 = sb - 2*lane + 256
    const int base0 = 8 * (sb - 2 * lane + 256);
    LD4(Av0, Av1, Av2, Av3, base0);                 // g0: entries 0..7

    float* wbase = (lane == 63) ? &bndX[wwr][sb + 1] : &dumpA[wvs][lane];

    STEP(0); STEP(1); STEP(2);
    LD4(Bv0, Bv1, Bv2, Bv3, base0 + 64);            // g1: entries 8..15 (first use r=8)
    STEP(3); STEP(4); STEP(5); STEP(6); STEP(7); STEP(8); STEP(9);
    LD4(Av0, Av1, Av2, Av3, base0 + 128);           // g2: entries 16..23 (first use r=16)
    STEP(10); STEP(11); STEP(12); STEP(13); STEP(14); STEP(15); STEP(16); STEP(17);
    LD4(Bv0, Bv1, Bv2, Bv3, base0 + 192);           // g3: entries 24..31 (first use r=24)
    STEP(18); STEP(19); STEP(20); STEP(21); STEP(22); STEP(23);
    STEP(24); STEP(25); STEP(26); STEP(27); STEP(28); STEP(29); STEP(30); STEP(31);
    __syncthreads();
  }

  if (isProd) {   // backstop: re-export the full boundary row (guarantees final cols)
    for (int c0 = lane; c0 <= LL; c0 += 64)
      __hip_atomic_store((int*)(gcols + c0), __float_as_int(bndX[4][c0 + BOFF]),
                         __ATOMIC_RELAXED, __HIP_MEMORY_SCOPE_AGENT);
  }

  // final cell (1024,1024): WG1 wave 3 lane 63 row b at s = 1151
  if (wg == 1 && t == NT - 1) wsf[bb] = costL + CLOG * __builtin_amdgcn_logf(lastmm);
}

__global__ void reduce_mean(const float* __restrict__ ws, float* __restrict__ out) {
  if (threadIdx.x == 0 && blockIdx.x == 0) {
    float s = 0.f;
    for (int i = 0; i < NB; ++i) s += ws[i];
    out[0] = s * (1.0f / NB);
  }
}

extern "C" void kernel_launch(void* const* d_in, const int* in_sizes, int n_in,
                              void* d_out, int out_size, void* d_ws, size_t ws_size,
                              hipStream_t stream) {
  const float* o  = (const float*)d_in[0];
  const float* tg = (const float*)d_in[1];
  float* ws  = (float*)d_ws;
  float* out = (float*)d_out;

  dtw_kernel<<<2 * NB, NT, 0, stream>>>(o, tg, ws);
  reduce_mean<<<1, 64, 0, stream>>>(ws, out);
}

// Round 7
// 92.543 us; speedup vs baseline: 6.1555x; 1.3405x over previous
//
#include <hip/hip_runtime.h>

#define LL    1024
#define NB    8
#define NT    256          // 4 waves per WG
#define KCH   32           // steps per chunk (one barrier per chunk)
#define SKEW  96           // intra-WG wave skew = 64 rows + KCH
#define SMAX  1087         // last local step (lane 63: 63 + 1024)
#define NCH   45           // compute chunks (<=42) + trailing export chunks
#define YTN   1536         // y-table entries (float2)
#define BROW  1160         // bndX row stride (floats)
#define BOFF  128          // col 0 of a boundary row at index BOFF
#define GBASE 64           // d_ws float offset of link regions
#define GSTR  1280         // per-link region stride (floats): 128 guard + 1025 + pad
#define C10   14.426950408889634f        // 10*log2(e)
#define CLOG  (-0.069314718055994531f)   // -(ln2)/10
#define EPS3  1e-12f

// Soft-DTW in e-space (e = exp(-10*D)); 16 strips x 64 rows across 4 WGs/batch.
// Lane l owns one row; up/diag neighbor via wave_shr:1 DPP (no LDS round-trip).
// Intra-WG strip handoff: LDS boundary rows + chunk preload + readlane.
// Inter-WG handoff: relaxed agent-scope atomics, sentinel-validated, with
// double-covered export windows + full backstop sweep (round-6 proven).

#define YB4(k) ((((k) >> 3) & 1)                                               \
    ? (((((k) & 7) >> 1) == 0) ? Bv0 : ((((k) & 7) >> 1) == 1) ? Bv1           \
                               : ((((k) & 7) >> 1) == 2) ? Bv2 : Bv3)          \
    : (((((k) & 7) >> 1) == 0) ? Av0 : ((((k) & 7) >> 1) == 1) ? Av1           \
                               : ((((k) & 7) >> 1) == 2) ? Av2 : Av3))
#define FPE(k) (((k) & 1) ? YB4(k).z : YB4(k).x)
#define FNE(k) (((k) & 1) ? YB4(k).w : YB4(k).y)

// Cell (lane+1, j) at local step s = lane + j; entry ji = s - lane + 256.
#define STEP(r) do {                                                           \
    const float fp_ = FPE(r);                                                  \
    const float fn_ = FNE(r);                                                  \
    const float dppv_ = __int_as_float(__builtin_amdgcn_update_dpp(            \
        0, __float_as_int(E1), 0x138, 0xf, 0xf, true)); /* wave_shr:1 */       \
    const float bvs_ = __int_as_float(                                         \
        __builtin_amdgcn_readlane(__float_as_int(B), (r)));                    \
    const float upa_ = isL0 ? bvs_ : dppv_;                                    \
    const float eca_ = fminf(EN0 * fp_, EP0 * fn_);                            \
    const float mma_ = fmaf(up_del + E1 + upa_, (1.f / 3.f), EPS3);            \
    const float nva_ = eca_ * mma_;                                            \
    wbase[(r)] = nva_;                                                         \
    E1 = nva_; up_del = upa_; lastmm = mma_;                                   \
  } while (0)

#define LD4(d0, d1, d2, d3, byteoff) do {                                      \
    const char* p_ = ytp + (byteoff);                                          \
    d0 = *(const float4*)(p_);                                                 \
    d1 = *(const float4*)(p_ + 16);                                            \
    d2 = *(const float4*)(p_ + 32);                                            \
    d3 = *(const float4*)(p_ + 48);                                            \
  } while (0)

__global__ __launch_bounds__(NT, 1) void dtw_kernel(const float* __restrict__ outp,
                                                    const float* __restrict__ tgtp,
                                                    float* __restrict__ wsf) {
  const int bb = blockIdx.x >> 2;      // batch
  const int wg = blockIdx.x & 3;       // quarter: rows 256*wg+1 .. 256*wg+256
  const int t = threadIdx.x;
  const int lane = t & 63;
  const int wvs = __builtin_amdgcn_readfirstlane(t >> 6);

  __shared__ float2 ytabA[YTN];       // (fp,fn) at slot ji        (even lanes)
  __shared__ float2 ytabB[YTN];       // (fp,fn) at slot ji - 1    (odd lanes)
  __shared__ float  bndX[5][BROW];    // 0-2: waves 0-2 boundaries; 3: zeros+seed; 4: wave-3 staging
  __shared__ float  dumpA[4][128];    // LDS sink for non-lane-63 staging writes

  {
    float4* za = (float4*)&ytabA[0];
    for (int i = t; i < (YTN * 2) / 4; i += NT) za[i] = make_float4(0.f, 0.f, 0.f, 0.f);
    float4* zb2 = (float4*)&ytabB[0];
    for (int i = t; i < (YTN * 2) / 4; i += NT) zb2[i] = make_float4(0.f, 0.f, 0.f, 0.f);
    float4* zb = (float4*)&bndX[0][0];
    for (int i = t; i < (5 * BROW) / 4; i += NT) zb[i] = make_float4(0.f, 0.f, 0.f, 0.f);
  }
  __syncthreads();

  const float* xb = outp + (size_t)bb * LL * LL;
  const float* yb = tgtp + (size_t)bb * LL * LL;

  // my row: global row 256*wg + 64*wvs + lane + 1
  const float xd = xb[256 * wg + 64 * wvs + lane];
  const float EP0 = __builtin_amdgcn_exp2f( C10 * xd);
  const float EN0 = __builtin_amdgcn_exp2f(-C10 * xd);

  {
    const float4 yv = *(const float4*)(yb + 4 * t);
    const float yy[4] = {yv.x, yv.y, yv.z, yv.w};
#pragma unroll
    for (int q = 0; q < 4; ++q) {
      const int ji = (4 * t + 1 + q) + 256;          // j in [1,1024]
      const float2 v = make_float2(__builtin_amdgcn_exp2f( C10 * yy[q]),
                                   __builtin_amdgcn_exp2f(-C10 * yy[q]));
      ytabA[ji] = v;
      ytabB[ji - 1] = v;
    }
  }
  if (wg == 0 && t == 0) bndX[3][BOFF] = 1.0f;      // e[0,0] = 1 seed
  const float costL = (wg == 3 && t == NT - 1) ? fabsf(xd - yb[LL - 1]) : 0.f;
  __syncthreads();

  float E1 = 0.f, up_del = 0.f, lastmm = EPS3;
  float4 Av0, Av1, Av2, Av3;
  float4 Bv0 = make_float4(0.f, 0.f, 0.f, 0.f), Bv1 = Bv0, Bv2 = Bv0, Bv3 = Bv0;
  Av0 = Bv0; Av1 = Bv0; Av2 = Bv0; Av3 = Bv0;
  const bool isL0 = (lane == 0);
  const int wprev = (wvs == 0) ? 3 : (wvs - 1);
  const int wwr   = (wvs == 3) ? 4 : wvs;
  const bool isProd = (wg < 3) && (wvs == 3);
  const bool isCons = (wg > 0) && (wvs == 0);
  // per-lane y-table view: 16B-aligned for every lane via the dual table
  const char* ytp = (lane & 1) ? (const char*)ytabB : (const char*)ytabA;
  const int   loff = 8 * (((lane & 1) ? 255 : 256) - lane);

  float* gprod = wsf + GBASE + (bb * 3 + wg)     * GSTR + 128;  // valid when wg<3
  float* gcons = wsf + GBASE + (bb * 3 + wg - 1) * GSTR + 128;  // valid when wg>0

  float Bnext = 0.f;
  int*  pcur  = (int*)gcons;
  if (isCons) {
    for (int c0 = lane; c0 <= LL; c0 += 64)
      __hip_atomic_store((int*)(gcons + c0), __float_as_int(-1.0f),
                         __ATOMIC_RELAXED, __HIP_MEMORY_SCOPE_AGENT);
    __threadfence();
    pcur = (int*)(gcons + lane);
    Bnext = __int_as_float(__hip_atomic_load(pcur, __ATOMIC_RELAXED, __HIP_MEMORY_SCOPE_AGENT));
  }

#pragma unroll 1
  for (int c = 0; c < NCH; ++c) {
    const int sb = KCH * c - SKEW * wvs;   // local step at r=0 (multiple of 32)

    if (isProd && sb >= 64) {              // export window [sb-127, sb-64] (double-covered)
      int ec = sb - 127 + lane;
      ec = ec < 0 ? 0 : (ec > LL ? LL : ec);
      const float ev = bndX[4][ec + BOFF];
      __hip_atomic_store((int*)(gprod + ec), __float_as_int(ev),
                         __ATOMIC_RELAXED, __HIP_MEMORY_SCOPE_AGENT);
    }

    if (sb < 0 || sb > SMAX - (KCH - 1)) { __syncthreads(); continue; }

    // boundary preload: lane l holds up-value for step sb+l (col sb+l); r<32 used
    float B;
    if (isCons) {
      float bv = Bnext;
      for (int tries = 0;
           (__ballot(bv < 0.f) & 0xffffffffull) && tries < (1 << 16); ++tries) {
        __builtin_amdgcn_s_sleep(8);
        bv = __int_as_float(__hip_atomic_load(pcur, __ATOMIC_RELAXED, __HIP_MEMORY_SCOPE_AGENT));
      }
      B = bv;
      int cn = sb + KCH + lane; cn = cn > LL ? LL : cn;       // prefetch next chunk
      pcur = (int*)(gcons + cn);
      Bnext = __int_as_float(__hip_atomic_load(pcur, __ATOMIC_RELAXED, __HIP_MEMORY_SCOPE_AGENT));
    } else {
      int colp = sb + lane; colp = colp > LL ? LL : colp;
      B = bndX[wprev][colp + BOFF];
    }

    // y-stream chunk loads: entry ji = sb + r - lane + 256, groups of 8
    const int base0 = loff + 8 * sb;
    LD4(Av0, Av1, Av2, Av3, base0);                 // g0: entries 0..7

    // staging: lane 63 -> boundary row (col sb+r-63 at index sb+65+r), else sink
    float* wbase = (lane == 63) ? &bndX[wwr][sb + 65] : &dumpA[wvs][lane];

    STEP(0); STEP(1); STEP(2);
    LD4(Bv0, Bv1, Bv2, Bv3, base0 + 64);            // g1: entries 8..15 (first use r=8)
    STEP(3); STEP(4); STEP(5); STEP(6); STEP(7); STEP(8); STEP(9);
    LD4(Av0, Av1, Av2, Av3, base0 + 128);           // g2: entries 16..23 (first use r=16)
    STEP(10); STEP(11); STEP(12); STEP(13); STEP(14); STEP(15); STEP(16); STEP(17);
    LD4(Bv0, Bv1, Bv2, Bv3, base0 + 192);           // g3: entries 24..31 (first use r=24)
    STEP(18); STEP(19); STEP(20); STEP(21); STEP(22); STEP(23);
    STEP(24); STEP(25); STEP(26); STEP(27); STEP(28); STEP(29); STEP(30); STEP(31);
    __syncthreads();
  }

  if (isProd) {   // backstop: full boundary-row sweep (guarantees every col)
    for (int c0 = lane; c0 <= LL; c0 += 64)
      __hip_atomic_store((int*)(gprod + c0), __float_as_int(bndX[4][c0 + BOFF]),
                         __ATOMIC_RELAXED, __HIP_MEMORY_SCOPE_AGENT);
  }

  // final cell (1024,1024): WG3 wave 3 lane 63 at s = 1087 (chunk sb=1056, r=31)
  if (wg == 3 && t == NT - 1) wsf[bb] = costL + CLOG * __builtin_amdgcn_logf(lastmm);
}

__global__ void reduce_mean(const float* __restrict__ ws, float* __restrict__ out) {
  if (threadIdx.x == 0 && blockIdx.x == 0) {
    float s = 0.f;
    for (int i = 0; i < NB; ++i) s += ws[i];
    out[0] = s * (1.0f / NB);
  }
}

extern "C" void kernel_launch(void* const* d_in, const int* in_sizes, int n_in,
                              void* d_out, int out_size, void* d_ws, size_t ws_size,
                              hipStream_t stream) {
  const float* o  = (const float*)d_in[0];
  const float* tg = (const float*)d_in[1];
  float* ws  = (float*)d_ws;
  float* out = (float*)d_out;

  dtw_kernel<<<4 * NB, NT, 0, stream>>>(o, tg, ws);
  reduce_mean<<<1, 64, 0, stream>>>(ws, out);
}